// Round 1
// baseline (755.801 us; speedup 1.0000x reference)
//
#include <hip/hip_runtime.h>

// OverlapWindowMHA2d on MI355X (gfx950).
// Pipeline: prep (w -> bf16) ; fused qkv+attention (branch1, branch2) ; head GEMM.
// Workspace layout (needs ~101.3 MB):
//   [0)            o_cat bf16 [b][win(1024)][n(16)][c(384)]   = 100,663,296 B
//   [+100663296)   w_qkv1 bf16 (576x192)                      =     221,184 B
//   [+100884480)   w_qkv2 bf16 (576x192)                      =     221,184 B
//   [+101105664)   w_head bf16 (192x384)                      =     147,456 B

typedef unsigned short u16;
using bf16x8 = __attribute__((ext_vector_type(8))) short;   // 8 bf16 (4 VGPRs) — per guide, verified on gfx950
using f32x4  = __attribute__((ext_vector_type(4))) float;
using u16x8  = __attribute__((ext_vector_type(8))) unsigned short;
using u16x4  = __attribute__((ext_vector_type(4))) unsigned short;

#define BATCH 8
#define CIN   192
#define HSZ   128
#define WSZ   128
#define CQKV  576
#define NHEADS 6
#define HD    32
#define NW1   32          // 128/4 windows per dim, branch 1
#define NW2   33          // 132/4 windows per dim, branch 2 (padded)
#define WIN_PER_B 1024    // 32*32

__device__ __forceinline__ float bf2f(u16 u) {
    unsigned int x = ((unsigned int)u) << 16;
    float f; __builtin_memcpy(&f, &x, 4); return f;
}
__device__ __forceinline__ u16 f2bf(float f) {
    unsigned int x; __builtin_memcpy(&x, &f, 4);
    unsigned int r = (x + 0x7FFFu + ((x >> 16) & 1u)) >> 16;
    return (u16)r;
}
__device__ __forceinline__ void ld8f(const u16* p, float* f) {
    u16x8 v = *reinterpret_cast<const u16x8*>(p);
#pragma unroll
    for (int j = 0; j < 8; ++j) f[j] = bf2f(v[j]);
}

// ---------------------------------------------------------------------------
// prep: f32 -> bf16 weight conversion
// ---------------------------------------------------------------------------
__global__ void prep_conv(const float* __restrict__ w1, const float* __restrict__ w2,
                          const float* __restrict__ wh,
                          u16* __restrict__ w1b, u16* __restrict__ w2b, u16* __restrict__ whb) {
    int i = blockIdx.x * 256 + threadIdx.x;           // 294912 total
    if (i < 110592)        w1b[i] = f2bf(w1[i]);
    else if (i < 221184)   w2b[i - 110592] = f2bf(w2[i - 110592]);
    else                   whb[i - 221184] = f2bf(wh[i - 221184]);
}

// ---------------------------------------------------------------------------
// Fused QKV (MFMA) + attention (f32) per 2 windows. BR=0: branch1, BR=1: branch2.
// o_cat write: BR=0 -> channels [0,192), BR=1 -> channels [192,384) with crop remap.
// ---------------------------------------------------------------------------
template<int BR>
__global__ __launch_bounds__(256, 2) void qkv_attn(const float* __restrict__ x,
                                                   const u16* __restrict__ wb,
                                                   const float* __restrict__ bias,
                                                   u16* __restrict__ ocat) {
    __shared__ __align__(16) u16 x_lds[32][200];      // [tok][c], padded stride
    __shared__ __align__(16) char wq_raw[46080];      // w stage (576x40 u16) / qkv restage (32x584 u16)
    __shared__ float bias_lds[CQKV];

    const int tid  = threadIdx.x;
    const int wave = tid >> 6, lane = tid & 63;
    const int lo16 = lane & 15, quad = lane >> 4;

    int b, wy, wx0;
    if (BR == 0) {
        int bi = blockIdx.x;                // 8*32*16 = 4096
        b = bi >> 9; int rem = bi & 511;
        wy = rem >> 4; wx0 = (rem & 15) * 2;
    } else {
        int bi = blockIdx.x;                // 8*33*17 = 4488
        b = bi / 561; int rem = bi % 561;
        wy = rem / 17; wx0 = (rem % 17) * 2;
    }

    for (int i = tid; i < CQKV; i += 256) bias_lds[i] = bias[i];

    // --- load x tile (2 windows x 16 tokens x 192 ch) into LDS as bf16 ---
    for (int i = tid; i < 1536; i += 256) {           // win(2) * c(192) * y(4)
        int win = i / 768, r = i % 768;
        int c = r >> 2, y = r & 3;
        int tok = win * 16 + y * 4;
        if (BR == 0) {
            int h = wy * 4 + y;
            const float4 v4 = *reinterpret_cast<const float4*>(
                &x[(((size_t)b * CIN + c) * HSZ + h) * WSZ + (wx0 + win) * 4]);
            x_lds[tok + 0][c] = f2bf(v4.x);
            x_lds[tok + 1][c] = f2bf(v4.y);
            x_lds[tok + 2][c] = f2bf(v4.z);
            x_lds[tok + 3][c] = f2bf(v4.w);
        } else {
            int wx = wx0 + win;
            int h = wy * 4 + y - 2;
            bool hok = (wx < NW2) && (h >= 0) && (h < HSZ);
#pragma unroll
            for (int dx = 0; dx < 4; ++dx) {
                int w = wx * 4 + dx - 2;
                float v = (hok && w >= 0 && w < WSZ)
                              ? x[(((size_t)b * CIN + c) * HSZ + h) * WSZ + w] : 0.0f;
                x_lds[tok + dx][c] = f2bf(v);
            }
        }
    }
    __syncthreads();

    // --- MFMA: qkv[co 576][tok 32] = w(576x192) @ x(192x32), K in 6 steps ---
    u16* wlds = reinterpret_cast<u16*>(wq_raw);
    f32x4 acc[9][2];
#pragma unroll
    for (int mt = 0; mt < 9; ++mt)
#pragma unroll
        for (int nt = 0; nt < 2; ++nt) acc[mt][nt] = f32x4{0.f, 0.f, 0.f, 0.f};

    for (int s = 0; s < 6; ++s) {
        // stage w chunk [576][32] (stride 40 for bank spread)
        for (int i = tid; i < 2304; i += 256) {
            int co = i >> 2, kk = (i & 3) * 8;
            u16x8 v = *reinterpret_cast<const u16x8*>(&wb[co * 192 + s * 32 + kk]);
            *reinterpret_cast<u16x8*>(&wlds[co * 40 + kk]) = v;
        }
        __syncthreads();
        bf16x8 bfr[2];
#pragma unroll
        for (int nt = 0; nt < 2; ++nt)
            bfr[nt] = *reinterpret_cast<const bf16x8*>(&x_lds[nt * 16 + lo16][s * 32 + quad * 8]);
#pragma unroll
        for (int mt = 0; mt < 9; ++mt) {
            bf16x8 afr = *reinterpret_cast<const bf16x8*>(
                &wlds[(wave * 144 + mt * 16 + lo16) * 40 + quad * 8]);
            acc[mt][0] = __builtin_amdgcn_mfma_f32_16x16x32_bf16(afr, bfr[0], acc[mt][0], 0, 0, 0);
            acc[mt][1] = __builtin_amdgcn_mfma_f32_16x16x32_bf16(afr, bfr[1], acc[mt][1], 0, 0, 0);
        }
        __syncthreads();
    }

    // --- restage qkv (+bias, ->bf16) to LDS [tok 32][co 576] stride 584 ---
    {
        u16* qlds = reinterpret_cast<u16*>(wq_raw);
#pragma unroll
        for (int mt = 0; mt < 9; ++mt) {
            int co0 = wave * 144 + mt * 16 + quad * 4;
#pragma unroll
            for (int nt = 0; nt < 2; ++nt) {
                int tok = nt * 16 + lo16;
                u16x4 pk;
#pragma unroll
                for (int r = 0; r < 4; ++r) pk[r] = f2bf(acc[mt][nt][r] + bias_lds[co0 + r]);
                *reinterpret_cast<u16x4*>(&qlds[tok * 584 + co0]) = pk;
            }
        }
    }
    __syncthreads();

    // --- attention: thread = (win, head, row n); softmax row-local ---
    if (tid < 192) {
        const u16* qlds = reinterpret_cast<const u16*>(wq_raw);
        int win = tid / 96;
        int head = (tid % 96) / 16;
        int n = tid & 15;
        int tokbase = win * 16;
        const float scale = 0.1767766952966369f;   // 1/sqrt(32)

        float q[32];
#pragma unroll
        for (int g = 0; g < 4; ++g) ld8f(&qlds[(tokbase + n) * 584 + head * 32 + g * 8], &q[g * 8]);
#pragma unroll
        for (int d = 0; d < 32; ++d) q[d] *= scale;

        float lg[16];
        float mx = -1e30f;
#pragma unroll
        for (int m = 0; m < 16; ++m) {
            const u16* kp = &qlds[(tokbase + m) * 584 + 192 + head * 32];
            float a = 0.f;
#pragma unroll
            for (int g = 0; g < 4; ++g) {
                float kf[8]; ld8f(kp + g * 8, kf);
#pragma unroll
                for (int j = 0; j < 8; ++j) a += q[g * 8 + j] * kf[j];
            }
            lg[m] = a; mx = fmaxf(mx, a);
        }
        float ssum = 0.f;
#pragma unroll
        for (int m = 0; m < 16; ++m) { lg[m] = __expf(lg[m] - mx); ssum += lg[m]; }
        float inv = 1.0f / ssum;

        float o[32];
#pragma unroll
        for (int d = 0; d < 32; ++d) o[d] = 0.f;
#pragma unroll
        for (int m = 0; m < 16; ++m) {
            float p = lg[m] * inv;
            const u16* vp = &qlds[(tokbase + m) * 584 + 384 + head * 32];
#pragma unroll
            for (int g = 0; g < 4; ++g) {
                float vf[8]; ld8f(vp + g * 8, vf);
#pragma unroll
                for (int j = 0; j < 8; ++j) o[g * 8 + j] += p * vf[j];
            }
        }

        // store o -> o_cat (token-major), 64B contiguous per thread
        bool dov; size_t dst = 0;
        if (BR == 0) {
            int wg = wy * NW1 + wx0 + win;
            dst = (((size_t)(b * WIN_PER_B + wg)) * 16 + n) * 384 + head * 32;
            dov = true;
        } else {
            int wx = wx0 + win;
            int h = wy * 4 + (n >> 2) - 2;
            int w = wx * 4 + (n & 3) - 2;
            dov = (wx < NW2) && h >= 0 && h < HSZ && w >= 0 && w < WSZ;
            if (dov) {
                int wg = (h >> 2) * NW1 + (w >> 2);
                int nn = (h & 3) * 4 + (w & 3);
                dst = (((size_t)(b * WIN_PER_B + wg)) * 16 + nn) * 384 + 192 + head * 32;
            }
        }
        if (dov) {
#pragma unroll
            for (int g = 0; g < 4; ++g) {
                u16x8 pk;
#pragma unroll
                for (int j = 0; j < 8; ++j) pk[j] = f2bf(o[g * 8 + j]);
                *reinterpret_cast<u16x8*>(&ocat[dst + g * 8]) = pk;
            }
        }
    }
}

// ---------------------------------------------------------------------------
// head GEMM: out[b][co 192][h][w] = sum_c w_head[co][c] * o_cat[b][win][n][c] + b_head[co]
// Direct-from-global MFMA (no LDS). Block: M=192 (4 waves x 48), N=64 tokens (4 windows).
// ---------------------------------------------------------------------------
__global__ __launch_bounds__(256) void head_gemm(const u16* __restrict__ ocat,
                                                 const u16* __restrict__ whb,
                                                 const float* __restrict__ bh,
                                                 float* __restrict__ out) {
    const int tid = threadIdx.x;
    const int wave = tid >> 6, lane = tid & 63;
    const int lo16 = lane & 15, quad = lane >> 4;

    int bi = blockIdx.x;                    // 8*32*8 = 2048
    int b = bi >> 8; int rem = bi & 255;
    int wy = rem >> 3, wx0 = (rem & 7) * 4;
    int co_base = wave * 48;

    f32x4 acc[3][4];
#pragma unroll
    for (int mt = 0; mt < 3; ++mt)
#pragma unroll
        for (int nt = 0; nt < 4; ++nt) acc[mt][nt] = f32x4{0.f, 0.f, 0.f, 0.f};

    const int wg0 = wy * NW1 + wx0;
    const size_t obase = (((size_t)(b * WIN_PER_B + wg0)) * 16 + lo16) * 384 + quad * 8;

#pragma unroll 2
    for (int s = 0; s < 12; ++s) {
        int k0 = s * 32;
        bf16x8 a[3], bb[4];
#pragma unroll
        for (int nt = 0; nt < 4; ++nt)
            bb[nt] = *reinterpret_cast<const bf16x8*>(&ocat[obase + (size_t)nt * 6144 + k0]);
#pragma unroll
        for (int mt = 0; mt < 3; ++mt)
            a[mt] = *reinterpret_cast<const bf16x8*>(
                &whb[(size_t)(co_base + mt * 16 + lo16) * 384 + k0 + quad * 8]);
#pragma unroll
        for (int mt = 0; mt < 3; ++mt)
#pragma unroll
            for (int nt = 0; nt < 4; ++nt)
                acc[mt][nt] = __builtin_amdgcn_mfma_f32_16x16x32_bf16(a[mt], bb[nt], acc[mt][nt], 0, 0, 0);
    }

    int h = wy * 4 + (lo16 >> 2);
#pragma unroll
    for (int mt = 0; mt < 3; ++mt) {
        int co = co_base + mt * 16 + quad * 4;
#pragma unroll
        for (int r = 0; r < 4; ++r) {
            float bias = bh[co + r];
#pragma unroll
            for (int nt = 0; nt < 4; ++nt) {
                int w = (wx0 + nt) * 4 + (lo16 & 3);
                out[(((size_t)b * CIN + co + r) * HSZ + h) * WSZ + w] = acc[mt][nt][r] + bias;
            }
        }
    }
}

// ---------------------------------------------------------------------------
extern "C" void kernel_launch(void* const* d_in, const int* in_sizes, int n_in,
                              void* d_out, int out_size, void* d_ws, size_t ws_size,
                              hipStream_t stream) {
    const float* x  = (const float*)d_in[0];
    const float* w1 = (const float*)d_in[1];
    const float* b1 = (const float*)d_in[2];
    const float* w2 = (const float*)d_in[3];
    const float* b2 = (const float*)d_in[4];
    const float* wh = (const float*)d_in[5];
    const float* bh = (const float*)d_in[6];
    float* out = (float*)d_out;

    char* ws = (char*)d_ws;
    u16* ocat = (u16*)ws;
    u16* w1b  = (u16*)(ws + 100663296);
    u16* w2b  = (u16*)(ws + 100884480);
    u16* whb  = (u16*)(ws + 101105664);

    prep_conv<<<1152, 256, 0, stream>>>(w1, w2, wh, w1b, w2b, whb);
    qkv_attn<0><<<4096, 256, 0, stream>>>(x, w1b, b1, ocat);
    qkv_attn<1><<<4488, 256, 0, stream>>>(x, w2b, b2, ocat);
    head_gemm<<<2048, 256, 0, stream>>>(ocat, whb, bh, out);
}

// Round 2
// 454.667 us; speedup vs baseline: 1.6623x; 1.6623x over previous
//
#include <hip/hip_runtime.h>

// OverlapWindowMHA2d on MI355X (gfx950) — R1.
// prep (w->bf16) ; fused qkv+MFMA-attention (branch1, branch2) ; head GEMM (LDS-staged B).
// Workspace layout (~101.3 MB):
//   [0)            o_cat bf16 [b][win(1024)][n(16)][c(384)]   = 100,663,296 B
//   [+100663296)   w_qkv1 bf16 (576x192)
//   [+100884480)   w_qkv2 bf16 (576x192)
//   [+101105664)   w_head bf16 (192x384)

typedef unsigned short u16;
using bf16x8 = __attribute__((ext_vector_type(8))) short;
using f32x4  = __attribute__((ext_vector_type(4))) float;
using u16x8  = __attribute__((ext_vector_type(8))) unsigned short;
using u16x4  = __attribute__((ext_vector_type(4))) unsigned short;

#define CIN   192
#define CQKV  576
#define NW2   33

__device__ __forceinline__ float bf2f(u16 u) {
    unsigned int x = ((unsigned int)u) << 16;
    float f; __builtin_memcpy(&f, &x, 4); return f;
}
__device__ __forceinline__ u16 f2bf(float f) {
    unsigned int x; __builtin_memcpy(&x, &f, 4);
    return (u16)((x + 0x7FFFu + ((x >> 16) & 1u)) >> 16);
}
// x-tile LDS column swizzle: spreads banks for the [tok][c] scalar writes while
// keeping 8-element (16B) k-blocks contiguous for b128 fragment reads.
__device__ __forceinline__ int xcol(int c, int tok) {
    int blk = (c >> 3) ^ ((tok ^ (tok >> 4)) & 7);     // blk stays < 24
    return blk * 8 + (c & 7);
}

__global__ void prep_conv(const float* __restrict__ w1, const float* __restrict__ w2,
                          const float* __restrict__ wh,
                          u16* __restrict__ w1b, u16* __restrict__ w2b, u16* __restrict__ whb) {
    int i = blockIdx.x * 256 + threadIdx.x;            // 294912 total
    if (i < 110592)        w1b[i] = f2bf(w1[i]);
    else if (i < 221184)   w2b[i - 110592] = f2bf(w2[i - 110592]);
    else                   whb[i - 221184] = f2bf(wh[i - 221184]);
}

// ---------------------------------------------------------------------------
// Fused QKV (MFMA, M=576 N=64 K=192) + MFMA attention. 4 windows per block.
// ---------------------------------------------------------------------------
template<int BR>
__global__ __launch_bounds__(256, 2) void qkv_attn(const float* __restrict__ x,
                                                   const u16* __restrict__ wb,
                                                   const float* __restrict__ bias,
                                                   u16* __restrict__ ocat) {
    // Phase1: xl [0,25600) pitch 200 u16 ; wl [25600,71680) pitch 40 u16
    // Phase2: qk [0,50176) pitch 392 u16 ; vT [50176,74752) [24][32][16] ; pl [74752,77824) [4][16][24]
    __shared__ __align__(16) char smem[77824];
    u16* xl = (u16*)smem;
    u16* wl = (u16*)(smem + 25600);
    u16* qk = (u16*)smem;
    u16* vt = (u16*)(smem + 50176);
    u16* pl = (u16*)(smem + 74752);

    const int tid  = threadIdx.x;
    const int wave = tid >> 6, lane = tid & 63;
    const int lo16 = lane & 15, quad = lane >> 4;

    int b, wy, g;
    if (BR == 0) {                       // 8 * 32 * 8 = 2048
        int bi = blockIdx.x;
        b = bi >> 8; int rem = bi & 255;
        wy = rem >> 3; g = rem & 7;
    } else {                             // 8 * 33 * 9 = 2376
        int bi = blockIdx.x;
        b = bi / 297; int rem = bi % 297;
        wy = rem / 9; g = rem % 9;
    }
    const int hbase = wy * 4, wbase = g * 16;

    // --- x tile: 4 windows x 16 tok x 192 ch -> LDS bf16, 64B-coalesced reads ---
#pragma unroll
    for (int it = 0; it < 12; ++it) {
        int i = it * 256 + tid;          // c(192) x y(4) x xc(4)
        int c = i >> 4, y = (i >> 2) & 3, xc = i & 3;
        float e0, e1, e2, e3;
        if (BR == 0) {
            const float4 v = *reinterpret_cast<const float4*>(
                &x[(((size_t)b * CIN + c) * 128 + hbase + y) * 128 + wbase + xc * 4]);
            e0 = v.x; e1 = v.y; e2 = v.z; e3 = v.w;
        } else {
            int h = hbase + y - 2;
            int w0 = wbase + xc * 4 - 2;
            bool hok = (unsigned)h < 128u;
            const float* row = &x[(((size_t)b * CIN + c) * 128 + h) * 128];
            if (hok && w0 >= 0 && w0 + 3 < 128) {
                float2 p0 = *reinterpret_cast<const float2*>(&row[w0]);
                float2 p1 = *reinterpret_cast<const float2*>(&row[w0 + 2]);
                e0 = p0.x; e1 = p0.y; e2 = p1.x; e3 = p1.y;
            } else {
                e0 = (hok && w0 >= 0 && w0 < 128)         ? row[w0]     : 0.f;
                e1 = (hok && w0+1 >= 0 && w0+1 < 128)     ? row[w0 + 1] : 0.f;
                e2 = (hok && w0+2 >= 0 && w0+2 < 128)     ? row[w0 + 2] : 0.f;
                e3 = (hok && w0+3 >= 0 && w0+3 < 128)     ? row[w0 + 3] : 0.f;
            }
        }
        int t0 = xc * 16 + y * 4;
        xl[(t0 + 0) * 200 + xcol(c, t0 + 0)] = f2bf(e0);
        xl[(t0 + 1) * 200 + xcol(c, t0 + 1)] = f2bf(e1);
        xl[(t0 + 2) * 200 + xcol(c, t0 + 2)] = f2bf(e2);
        xl[(t0 + 3) * 200 + xcol(c, t0 + 3)] = f2bf(e3);
    }
    __syncthreads();

    // --- MFMA: qkv[co 576][tok 64], K=192 in 6 chunks ---
    f32x4 acc[9][4];
#pragma unroll
    for (int mt = 0; mt < 9; ++mt)
#pragma unroll
        for (int nt = 0; nt < 4; ++nt) acc[mt][nt] = f32x4{0.f, 0.f, 0.f, 0.f};

    for (int s = 0; s < 6; ++s) {
#pragma unroll
        for (int it = 0; it < 9; ++it) {         // stage w chunk [576][32]
            int i = it * 256 + tid;
            int co = i >> 2, kk = (i & 3) * 8;
            u16x8 v = *reinterpret_cast<const u16x8*>(&wb[co * 192 + s * 32 + kk]);
            *reinterpret_cast<u16x8*>(&wl[co * 40 + kk]) = v;
        }
        __syncthreads();
        bf16x8 bfr[4];
#pragma unroll
        for (int nt = 0; nt < 4; ++nt) {
            int tok = nt * 16 + lo16;
            int kb = s * 4 + quad;
            bfr[nt] = *reinterpret_cast<const bf16x8*>(
                &xl[tok * 200 + (((kb ^ ((tok ^ (tok >> 4)) & 7)) << 3))]);
        }
#pragma unroll
        for (int mt = 0; mt < 9; ++mt) {
            bf16x8 afr = *reinterpret_cast<const bf16x8*>(
                &wl[(wave * 144 + mt * 16 + lo16) * 40 + quad * 8]);
#pragma unroll
            for (int nt = 0; nt < 4; ++nt)
                acc[mt][nt] = __builtin_amdgcn_mfma_f32_16x16x32_bf16(afr, bfr[nt], acc[mt][nt], 0, 0, 0);
        }
        __syncthreads();
    }

    // --- restage: Q (scaled) / K -> qk[tok][392] ; V -> vT transposed ---
    const float scale = 0.17677669529663687f;     // 1/sqrt(32)
#pragma unroll
    for (int mt = 0; mt < 9; ++mt) {
        int co0 = wave * 144 + mt * 16 + quad * 4;
        const float4 bv = *reinterpret_cast<const float4*>(&bias[co0]);
#pragma unroll
        for (int nt = 0; nt < 4; ++nt) {
            int tok = nt * 16 + lo16;
            float v0 = acc[mt][nt][0] + bv.x, v1 = acc[mt][nt][1] + bv.y;
            float v2 = acc[mt][nt][2] + bv.z, v3 = acc[mt][nt][3] + bv.w;
            if (co0 < 192) { v0 *= scale; v1 *= scale; v2 *= scale; v3 *= scale; }
            if (co0 < 384) {
                u16x4 pk = {f2bf(v0), f2bf(v1), f2bf(v2), f2bf(v3)};
                *reinterpret_cast<u16x4*>(&qk[tok * 392 + co0]) = pk;
            } else {
                int dh = co0 - 384;
                int head = dh >> 5, d0 = dh & 31;
                int win = tok >> 4, m = tok & 15;
                u16* vrow = &vt[((win * 6 + head) * 32 + d0) * 16 + m];
                vrow[0]  = f2bf(v0);
                vrow[16] = f2bf(v1);
                vrow[32] = f2bf(v2);
                vrow[48] = f2bf(v3);
            }
        }
    }
    __syncthreads();

    // --- attention: wave = window, 6 heads sequentially, all MFMA ---
    {
        const int win = wave;
        const u16* qbase = qk + (size_t)(win * 16) * 392;
        const bf16x8 z8 = {};
        const f32x4 zc = {0.f, 0.f, 0.f, 0.f};
        // precompute store mapping (per lane token n = lo16)
        bool dov; size_t dst = 0;
        if (BR == 0) {
            int wg = wy * 32 + g * 4 + win;
            dst = (((size_t)(b * 1024 + wg)) * 16 + lo16) * 384;
            dov = true;
        } else {
            int wx = g * 4 + win;
            int h = wy * 4 + (lo16 >> 2) - 2;
            int w = wx * 4 + (lo16 & 3) - 2;
            dov = (wx < NW2) && (unsigned)h < 128u && (unsigned)w < 128u;
            if (dov) {
                int wg = (h >> 2) * 32 + (w >> 2);
                int nn = (h & 3) * 4 + (w & 3);
                dst = (((size_t)(b * 1024 + wg)) * 16 + nn) * 384 + 192;
            }
        }
#pragma unroll
        for (int head = 0; head < 6; ++head) {
            bf16x8 kfr = *reinterpret_cast<const bf16x8*>(
                &qbase[lo16 * 392 + 192 + head * 32 + quad * 8]);
            bf16x8 qfr = *reinterpret_cast<const bf16x8*>(
                &qbase[lo16 * 392 + head * 32 + quad * 8]);
            f32x4 st = __builtin_amdgcn_mfma_f32_16x16x32_bf16(kfr, qfr, zc, 0, 0, 0);
            // softmax over m (rows: quad*4+r across quads)
            float mx = fmaxf(fmaxf(st[0], st[1]), fmaxf(st[2], st[3]));
            mx = fmaxf(mx, __shfl_xor(mx, 16));
            mx = fmaxf(mx, __shfl_xor(mx, 32));
            float p0 = __expf(st[0] - mx), p1 = __expf(st[1] - mx);
            float p2 = __expf(st[2] - mx), p3 = __expf(st[3] - mx);
            float sum = p0 + p1 + p2 + p3;
            sum += __shfl_xor(sum, 16);
            sum += __shfl_xor(sum, 32);
            float inv = 1.0f / sum;
            u16x4 pk = {f2bf(p0), f2bf(p1), f2bf(p2), f2bf(p3)};
            *reinterpret_cast<u16x4*>(&pl[(wave * 16 + lo16) * 24 + quad * 4]) = pk;
            bf16x8 pf = (quad < 2)
                ? *reinterpret_cast<const bf16x8*>(&pl[(wave * 16 + lo16) * 24 + quad * 8]) : z8;
            const u16* vbase = &vt[(win * 6 + head) * 32 * 16];
#pragma unroll
            for (int half = 0; half < 2; ++half) {
                bf16x8 av = (quad < 2)
                    ? *reinterpret_cast<const bf16x8*>(&vbase[(half * 16 + lo16) * 16 + quad * 8]) : z8;
                f32x4 o = __builtin_amdgcn_mfma_f32_16x16x32_bf16(av, pf, zc, 0, 0, 0);
                if (dov) {
                    u16x4 ok = {f2bf(o[0] * inv), f2bf(o[1] * inv),
                                f2bf(o[2] * inv), f2bf(o[3] * inv)};
                    *reinterpret_cast<u16x4*>(&ocat[dst + head * 32 + half * 16 + quad * 4]) = ok;
                }
            }
        }
    }
}

// ---------------------------------------------------------------------------
// head GEMM: out[b][co 192][h][w] = w_head(192x384) @ o_cat rows + bias.
// B tile (64 tok x 384) staged once in LDS; A direct from global (L2-hot).
// ---------------------------------------------------------------------------
__global__ __launch_bounds__(256, 3) void head_gemm(const u16* __restrict__ ocat,
                                                    const u16* __restrict__ whb,
                                                    const float* __restrict__ bh,
                                                    float* __restrict__ out) {
    __shared__ __align__(16) u16 bt[64 * 392];
    const int tid = threadIdx.x;
    const int wave = tid >> 6, lane = tid & 63;
    const int lo16 = lane & 15, quad = lane >> 4;

    int bi = blockIdx.x;                    // 8 * 32 * 8 = 2048
    int b = bi >> 8; int rem = bi & 255;
    int wy = rem >> 3, g = rem & 7;
    const int wg0 = wy * 32 + g * 4;
    const size_t gbase = ((size_t)(b * 1024 + wg0) * 16) * 384;

#pragma unroll
    for (int it = 0; it < 12; ++it) {       // 3072 chunks of 8 u16, contiguous
        int i = it * 256 + tid;
        u16x8 v = *reinterpret_cast<const u16x8*>(&ocat[gbase + (size_t)i * 8]);
        int row = i / 48, kc = i - row * 48;
        *reinterpret_cast<u16x8*>(&bt[row * 392 + kc * 8]) = v;
    }
    __syncthreads();

    const int co_base = wave * 48;
    f32x4 acc[3][4];
#pragma unroll
    for (int mt = 0; mt < 3; ++mt)
#pragma unroll
        for (int nt = 0; nt < 4; ++nt) acc[mt][nt] = f32x4{0.f, 0.f, 0.f, 0.f};

#pragma unroll
    for (int s = 0; s < 12; ++s) {
        int k0 = s * 32;
        bf16x8 a[3], bb[4];
#pragma unroll
        for (int nt = 0; nt < 4; ++nt)
            bb[nt] = *reinterpret_cast<const bf16x8*>(&bt[(nt * 16 + lo16) * 392 + k0 + quad * 8]);
#pragma unroll
        for (int mt = 0; mt < 3; ++mt)
            a[mt] = *reinterpret_cast<const bf16x8*>(
                &whb[(size_t)(co_base + mt * 16 + lo16) * 384 + k0 + quad * 8]);
#pragma unroll
        for (int mt = 0; mt < 3; ++mt)
#pragma unroll
            for (int nt = 0; nt < 4; ++nt)
                acc[mt][nt] = __builtin_amdgcn_mfma_f32_16x16x32_bf16(a[mt], bb[nt], acc[mt][nt], 0, 0, 0);
    }

    int h = wy * 4 + (lo16 >> 2);
#pragma unroll
    for (int mt = 0; mt < 3; ++mt) {
        int co0 = co_base + mt * 16 + quad * 4;
        const float4 bv = *reinterpret_cast<const float4*>(&bh[co0]);
#pragma unroll
        for (int r = 0; r < 4; ++r) {
            float bias = (r == 0) ? bv.x : (r == 1) ? bv.y : (r == 2) ? bv.z : bv.w;
#pragma unroll
            for (int nt = 0; nt < 4; ++nt) {
                int w = (g * 4 + nt) * 4 + (lo16 & 3);
                out[(((size_t)b * CIN + co0 + r) * 128 + h) * 128 + w] = acc[mt][nt][r] + bias;
            }
        }
    }
}

// ---------------------------------------------------------------------------
extern "C" void kernel_launch(void* const* d_in, const int* in_sizes, int n_in,
                              void* d_out, int out_size, void* d_ws, size_t ws_size,
                              hipStream_t stream) {
    const float* x  = (const float*)d_in[0];
    const float* w1 = (const float*)d_in[1];
    const float* b1 = (const float*)d_in[2];
    const float* w2 = (const float*)d_in[3];
    const float* b2 = (const float*)d_in[4];
    const float* wh = (const float*)d_in[5];
    const float* bh = (const float*)d_in[6];
    float* out = (float*)d_out;

    char* ws = (char*)d_ws;
    u16* ocat = (u16*)ws;
    u16* w1b  = (u16*)(ws + 100663296);
    u16* w2b  = (u16*)(ws + 100884480);
    u16* whb  = (u16*)(ws + 101105664);

    prep_conv<<<1152, 256, 0, stream>>>(w1, w2, wh, w1b, w2b, whb);
    qkv_attn<0><<<2048, 256, 0, stream>>>(x, w1b, b1, ocat);
    qkv_attn<1><<<2376, 256, 0, stream>>>(x, w2b, b2, ocat);
    head_gemm<<<2048, 256, 0, stream>>>(ocat, whb, bh, out);
}